// Round 1
// baseline (2952.437 us; speedup 1.0000x reference)
//
#include <hip/hip_runtime.h>

#define EMB 100

// ---------------- out = emb * scale (float4) ----------------
__global__ __launch_bounds__(256) void k_init_out(const float* __restrict__ emb,
                                                  float* __restrict__ out,
                                                  int n4, float scale) {
    int i = blockIdx.x * 256 + threadIdx.x;
    int stride = gridDim.x * 256;
    for (; i < n4; i += stride) {
        float4 v = ((const float4*)emb)[i];
        v.x *= scale; v.y *= scale; v.z *= scale; v.w *= scale;
        ((float4*)out)[i] = v;
    }
}

// ---------------- CSR build ----------------
__global__ __launch_bounds__(256) void k_hist(const int* __restrict__ rows,
                                              int* __restrict__ cnt, int E) {
    int i = blockIdx.x * 256 + threadIdx.x;
    if (i < E) atomicAdd(&cnt[rows[i]], 1);
}

__global__ __launch_bounds__(256) void k_scan1(const int* __restrict__ cnt,
                                               int* __restrict__ outp,
                                               int* __restrict__ bsum, int n) {
    __shared__ int tmp[256];
    int i = blockIdx.x * 256 + threadIdx.x;
    int v = (i < n) ? cnt[i] : 0;
    tmp[threadIdx.x] = v;
    __syncthreads();
    for (int off = 1; off < 256; off <<= 1) {
        int t = (threadIdx.x >= off) ? tmp[threadIdx.x - off] : 0;
        __syncthreads();
        tmp[threadIdx.x] += t;
        __syncthreads();
    }
    if (i < n) outp[i] = tmp[threadIdx.x] - v;   // exclusive
    if (threadIdx.x == 255) bsum[blockIdx.x] = tmp[255];
}

__global__ __launch_bounds__(1024) void k_scan2(int* __restrict__ bsum, int nb) {
    __shared__ int tmp[1024];
    int v = (threadIdx.x < nb) ? bsum[threadIdx.x] : 0;
    tmp[threadIdx.x] = v;
    __syncthreads();
    for (int off = 1; off < 1024; off <<= 1) {
        int t = (threadIdx.x >= off) ? tmp[threadIdx.x - off] : 0;
        __syncthreads();
        tmp[threadIdx.x] += t;
        __syncthreads();
    }
    if (threadIdx.x < nb) bsum[threadIdx.x] = tmp[threadIdx.x] - v; // exclusive
}

__global__ __launch_bounds__(256) void k_scan3(int* __restrict__ outp,
                                               const int* __restrict__ bsum,
                                               int n, int E) {
    int i = blockIdx.x * 256 + threadIdx.x;
    if (i < n) outp[i] += bsum[blockIdx.x];
    if (i == 0) outp[n] = E;
}

__global__ __launch_bounds__(256) void k_copy(int* __restrict__ dst,
                                              const int* __restrict__ src, int n) {
    int i = blockIdx.x * 256 + threadIdx.x;
    if (i < n) dst[i] = src[i];
}

__global__ __launch_bounds__(256) void k_scatter(const int* __restrict__ rows,
                                                 const int* __restrict__ cols,
                                                 const float* __restrict__ vals,
                                                 int* __restrict__ nextp,
                                                 int* __restrict__ cols_s,
                                                 float* __restrict__ vals_s, int E) {
    int i = blockIdx.x * 256 + threadIdx.x;
    if (i < E) {
        int r = rows[i];
        int pos = atomicAdd(&nextp[r], 1);
        cols_s[pos] = cols[i];
        vals_s[pos] = vals[i];
    }
}

// ---------------- GEMM: Y[n,e] = sum_d X[n,d] * W[e,d] ----------------
// One row per thread; the row lives in 100 VGPRs; W accesses are wave-uniform
// (scalar-load broadcast), so zero LDS.
__global__ __launch_bounds__(256) void k_gemm(const float* __restrict__ X,
                                              const float* __restrict__ W,
                                              float* __restrict__ Y, int N) {
    int row = blockIdx.x * 256 + threadIdx.x;
    if (row >= N) return;
    float x[EMB];
    const float* xp = X + (size_t)row * EMB;
#pragma unroll
    for (int d = 0; d < EMB; d += 4) {
        float4 v = *(const float4*)(xp + d);
        x[d] = v.x; x[d + 1] = v.y; x[d + 2] = v.z; x[d + 3] = v.w;
    }
    float* yp = Y + (size_t)row * EMB;
    for (int e = 0; e < EMB; e += 4) {
        const float* w0 = W + (size_t)(e + 0) * EMB;
        const float* w1 = W + (size_t)(e + 1) * EMB;
        const float* w2 = W + (size_t)(e + 2) * EMB;
        const float* w3 = W + (size_t)(e + 3) * EMB;
        float a0 = 0.f, a1 = 0.f, a2 = 0.f, a3 = 0.f;
#pragma unroll
        for (int d = 0; d < EMB; ++d) {
            float xd = x[d];
            a0 = fmaf(xd, w0[d], a0);
            a1 = fmaf(xd, w1[d], a1);
            a2 = fmaf(xd, w2[d], a2);
            a3 = fmaf(xd, w3[d], a3);
        }
        float4 r; r.x = a0; r.y = a1; r.z = a2; r.w = a3;
        *(float4*)(yp + e) = r;
    }
}

// ---------------- SpMM + norm + mean-accumulate ----------------
// One row per 128-thread block (2 waves); lane = dim (dims 100..127 idle).
// Xout gets the raw row; Out += raw/max(||raw||,eps) * scale.
__global__ __launch_bounds__(128) void k_spmm_norm(const int* __restrict__ row_ptr,
                                                   const int* __restrict__ cols_s,
                                                   const float* __restrict__ vals_s,
                                                   const float* __restrict__ Y,
                                                   float* __restrict__ Xout,
                                                   float* __restrict__ Out,
                                                   float scale) {
    int row = blockIdx.x;
    int tid = threadIdx.x;
    int beg = row_ptr[row], end = row_ptr[row + 1];
    float acc = 0.f;
    if (tid < EMB) {
        const float* ys = Y + tid;
        int j = beg;
        for (; j + 1 < end; j += 2) {
            int c0 = cols_s[j];
            int c1 = cols_s[j + 1];
            float v0 = vals_s[j];
            float v1 = vals_s[j + 1];
            acc = fmaf(v0, ys[(size_t)c0 * EMB], acc);
            acc = fmaf(v1, ys[(size_t)c1 * EMB], acc);
        }
        if (j < end) acc = fmaf(vals_s[j], ys[(size_t)cols_s[j] * EMB], acc);
    }
    float ss = acc * acc;
#pragma unroll
    for (int off = 32; off > 0; off >>= 1) ss += __shfl_down(ss, off, 64);
    __shared__ float s2[2];
    if ((tid & 63) == 0) s2[tid >> 6] = ss;
    __syncthreads();
    float norm = sqrtf(s2[0] + s2[1]);
    float sc = scale / fmaxf(norm, 1e-12f);
    if (tid < EMB) {
        size_t idx = (size_t)row * EMB + tid;
        Xout[idx] = acc;
        Out[idx] += acc * sc;
    }
}

extern "C" void kernel_launch(void* const* d_in, const int* in_sizes, int n_in,
                              void* d_out, int out_size, void* d_ws, size_t ws_size,
                              hipStream_t stream) {
    const float* emb   = (const float*)d_in[0];
    const float* avals = (const float*)d_in[1];
    const float* wts   = (const float*)d_in[2];
    const int*   arows = (const int*)d_in[3];
    const int*   acols = (const int*)d_in[4];

    const int N = in_sizes[0] / EMB;
    const int E = in_sizes[1];
    const int L = in_sizes[2] / (EMB * EMB);
    const float scale = 1.0f / (float)(L + 1);

    // workspace layout
    float* bufY   = (float*)d_ws;                       // N*EMB
    float* bufX   = bufY + (size_t)N * EMB;             // N*EMB
    int*   row_ptr = (int*)(bufX + (size_t)N * EMB);    // N+1 (+pad)
    int*   nextp   = row_ptr + (N + 2);                 // N
    int*   bsum    = nextp + N;                         // 1024
    int*   cols_s  = bsum + 1024;                       // E
    float* vals_s  = (float*)(cols_s + E);              // E
    float* out = (float*)d_out;

    const int nb_scan = (N + 255) / 256;

    // CSR build (adjacency is layer-invariant: build once, use 3x)
    hipMemsetAsync(nextp, 0, (size_t)N * sizeof(int), stream);
    k_hist<<<(E + 255) / 256, 256, 0, stream>>>(arows, nextp, E);
    k_scan1<<<nb_scan, 256, 0, stream>>>(nextp, row_ptr, bsum, N);
    k_scan2<<<1, 1024, 0, stream>>>(bsum, nb_scan);
    k_scan3<<<nb_scan, 256, 0, stream>>>(row_ptr, bsum, N, E);
    k_copy<<<nb_scan, 256, 0, stream>>>(nextp, row_ptr, N);
    k_scatter<<<(E + 255) / 256, 256, 0, stream>>>(arows, acols, avals, nextp,
                                                   cols_s, vals_s, E);

    // out = embedding * 1/(L+1)   (layer-0 term, NOT normalized)
    k_init_out<<<2048, 256, 0, stream>>>(emb, out, (N * EMB) / 4, scale);

    // layers
    const float* cur = emb;
    for (int l = 0; l < L; ++l) {
        k_gemm<<<(N + 255) / 256, 256, 0, stream>>>(
            cur, wts + (size_t)l * EMB * EMB, bufY, N);
        k_spmm_norm<<<N, 128, 0, stream>>>(row_ptr, cols_s, vals_s, bufY, bufX,
                                           out, scale);
        cur = bufX;
    }
}

// Round 2
// 2343.016 us; speedup vs baseline: 1.2601x; 1.2601x over previous
//
#include <hip/hip_runtime.h>

#define EMB 100
#define EMB2 50   // bf16 pairs per row

// ---- bf16 pair helpers (packed in uint: low ushort = even dim) ----
__device__ __forceinline__ float bflo(unsigned u) { return __uint_as_float(u << 16); }
__device__ __forceinline__ float bfhi(unsigned u) { return __uint_as_float(u & 0xFFFF0000u); }
__device__ __forceinline__ unsigned packbf(float a, float b) {
    unsigned ua = __float_as_uint(a), ub = __float_as_uint(b);
    unsigned ra = (ua + 0x7FFFu + ((ua >> 16) & 1u)) >> 16;   // RNE
    unsigned rb = (ub + 0x7FFFu + ((ub >> 16) & 1u)) >> 16;
    return ra | (rb << 16);
}

// ---------------- out = emb * scale (float4) ----------------
__global__ __launch_bounds__(256) void k_init_out(const float* __restrict__ emb,
                                                  float* __restrict__ out,
                                                  int n4, float scale) {
    int i = blockIdx.x * 256 + threadIdx.x;
    int stride = gridDim.x * 256;
    for (; i < n4; i += stride) {
        float4 v = ((const float4*)emb)[i];
        v.x *= scale; v.y *= scale; v.z *= scale; v.w *= scale;
        ((float4*)out)[i] = v;
    }
}

// ---------------- CSR build ----------------
__global__ __launch_bounds__(256) void k_hist(const int* __restrict__ rows,
                                              int* __restrict__ cnt, int E) {
    int i = blockIdx.x * 256 + threadIdx.x;
    if (i < E) atomicAdd(&cnt[rows[i]], 1);
}

__global__ __launch_bounds__(256) void k_scan1(const int* __restrict__ cnt,
                                               int* __restrict__ outp,
                                               int* __restrict__ bsum, int n) {
    __shared__ int tmp[256];
    int i = blockIdx.x * 256 + threadIdx.x;
    int v = (i < n) ? cnt[i] : 0;
    tmp[threadIdx.x] = v;
    __syncthreads();
    for (int off = 1; off < 256; off <<= 1) {
        int t = (threadIdx.x >= off) ? tmp[threadIdx.x - off] : 0;
        __syncthreads();
        tmp[threadIdx.x] += t;
        __syncthreads();
    }
    if (i < n) outp[i] = tmp[threadIdx.x] - v;   // exclusive
    if (threadIdx.x == 255) bsum[blockIdx.x] = tmp[255];
}

__global__ __launch_bounds__(1024) void k_scan2(int* __restrict__ bsum, int nb) {
    __shared__ int tmp[1024];
    int v = (threadIdx.x < nb) ? bsum[threadIdx.x] : 0;
    tmp[threadIdx.x] = v;
    __syncthreads();
    for (int off = 1; off < 1024; off <<= 1) {
        int t = (threadIdx.x >= off) ? tmp[threadIdx.x - off] : 0;
        __syncthreads();
        tmp[threadIdx.x] += t;
        __syncthreads();
    }
    if (threadIdx.x < nb) bsum[threadIdx.x] = tmp[threadIdx.x] - v; // exclusive
}

__global__ __launch_bounds__(256) void k_scan3(int* __restrict__ outp,
                                               const int* __restrict__ bsum,
                                               int n, int E) {
    int i = blockIdx.x * 256 + threadIdx.x;
    if (i < n) outp[i] += bsum[blockIdx.x];
    if (i == 0) outp[n] = E;
}

__global__ __launch_bounds__(256) void k_copy(int* __restrict__ dst,
                                              const int* __restrict__ src, int n) {
    int i = blockIdx.x * 256 + threadIdx.x;
    if (i < n) dst[i] = src[i];
}

__global__ __launch_bounds__(256) void k_scatter(const int* __restrict__ rows,
                                                 const int* __restrict__ cols,
                                                 const float* __restrict__ vals,
                                                 int* __restrict__ nextp,
                                                 int2* __restrict__ edges, int E) {
    int i = blockIdx.x * 256 + threadIdx.x;
    if (i < E) {
        int r = rows[i];
        int pos = atomicAdd(&nextp[r], 1);
        edges[pos] = make_int2(cols[i], __float_as_int(vals[i]));
    }
}

// ---------------- GEMM layer 0: X fp32 -> Y bf16 ----------------
// One row per thread; row in VGPRs; W wave-uniform scalar broadcast.
__global__ __launch_bounds__(256) void k_gemm_f32(const float* __restrict__ X,
                                                  const float* __restrict__ W,
                                                  unsigned* __restrict__ Y, int N) {
    int row = blockIdx.x * 256 + threadIdx.x;
    if (row >= N) return;
    float x[EMB];
    const float4* xp = (const float4*)(X + (size_t)row * EMB);
#pragma unroll
    for (int k = 0; k < EMB / 4; ++k) {
        float4 v = xp[k];
        x[4 * k] = v.x; x[4 * k + 1] = v.y; x[4 * k + 2] = v.z; x[4 * k + 3] = v.w;
    }
    unsigned* yp = Y + (size_t)row * EMB2;
    for (int e = 0; e < EMB; e += 4) {
        const float* w0 = W + (size_t)(e + 0) * EMB;
        const float* w1 = W + (size_t)(e + 1) * EMB;
        const float* w2 = W + (size_t)(e + 2) * EMB;
        const float* w3 = W + (size_t)(e + 3) * EMB;
        float a0 = 0.f, a1 = 0.f, a2 = 0.f, a3 = 0.f;
#pragma unroll
        for (int d = 0; d < EMB; ++d) {
            float xd = x[d];
            a0 = fmaf(xd, w0[d], a0);
            a1 = fmaf(xd, w1[d], a1);
            a2 = fmaf(xd, w2[d], a2);
            a3 = fmaf(xd, w3[d], a3);
        }
        uint2 r; r.x = packbf(a0, a1); r.y = packbf(a2, a3);
        *(uint2*)(yp + e / 2) = r;
    }
}

// ---------------- GEMM layers 1+: X bf16 -> Y bf16 ----------------
__global__ __launch_bounds__(256) void k_gemm_bf16(const unsigned* __restrict__ X,
                                                   const float* __restrict__ W,
                                                   unsigned* __restrict__ Y, int N) {
    int row = blockIdx.x * 256 + threadIdx.x;
    if (row >= N) return;
    float x[EMB];
    const uint2* xp = (const uint2*)(X + (size_t)row * EMB2);
#pragma unroll
    for (int k = 0; k < EMB2 / 2; ++k) {
        uint2 u = xp[k];
        x[4 * k]     = bflo(u.x); x[4 * k + 1] = bfhi(u.x);
        x[4 * k + 2] = bflo(u.y); x[4 * k + 3] = bfhi(u.y);
    }
    unsigned* yp = Y + (size_t)row * EMB2;
    for (int e = 0; e < EMB; e += 4) {
        const float* w0 = W + (size_t)(e + 0) * EMB;
        const float* w1 = W + (size_t)(e + 1) * EMB;
        const float* w2 = W + (size_t)(e + 2) * EMB;
        const float* w3 = W + (size_t)(e + 3) * EMB;
        float a0 = 0.f, a1 = 0.f, a2 = 0.f, a3 = 0.f;
#pragma unroll
        for (int d = 0; d < EMB; ++d) {
            float xd = x[d];
            a0 = fmaf(xd, w0[d], a0);
            a1 = fmaf(xd, w1[d], a1);
            a2 = fmaf(xd, w2[d], a2);
            a3 = fmaf(xd, w3[d], a3);
        }
        uint2 r; r.x = packbf(a0, a1); r.y = packbf(a2, a3);
        *(uint2*)(yp + e / 2) = r;
    }
}

// ---------------- SpMM + norm + mean-accumulate ----------------
// One 64-lane wave per row. Lanes 0..49 own a bf16 pair (dword gathers,
// 200 B/edge/wave). Edge loop unrolled x4 for MLP. Norm via shfl_xor.
__global__ __launch_bounds__(256) void k_spmm_norm(const int* __restrict__ row_ptr,
                                                   const int2* __restrict__ edges,
                                                   const unsigned* __restrict__ Y,
                                                   unsigned* __restrict__ Xout,
                                                   float* __restrict__ Out,
                                                   float scale, int writeX, int N) {
    int wave = (blockIdx.x * 256 + threadIdx.x) >> 6;
    int lane = threadIdx.x & 63;
    if (wave >= N) return;
    int row = wave;
    int beg = row_ptr[row], end = row_ptr[row + 1];
    float a0 = 0.f, a1 = 0.f;
    if (lane < EMB2) {
        const unsigned* yb = Y + lane;
        int j = beg;
        for (; j + 3 < end; j += 4) {
            int2 e0 = edges[j + 0];
            int2 e1 = edges[j + 1];
            int2 e2 = edges[j + 2];
            int2 e3 = edges[j + 3];
            unsigned y0 = yb[(size_t)e0.x * EMB2];
            unsigned y1 = yb[(size_t)e1.x * EMB2];
            unsigned y2 = yb[(size_t)e2.x * EMB2];
            unsigned y3 = yb[(size_t)e3.x * EMB2];
            float v0 = __int_as_float(e0.y), v1 = __int_as_float(e1.y);
            float v2 = __int_as_float(e2.y), v3 = __int_as_float(e3.y);
            a0 = fmaf(v0, bflo(y0), a0); a1 = fmaf(v0, bfhi(y0), a1);
            a0 = fmaf(v1, bflo(y1), a0); a1 = fmaf(v1, bfhi(y1), a1);
            a0 = fmaf(v2, bflo(y2), a0); a1 = fmaf(v2, bfhi(y2), a1);
            a0 = fmaf(v3, bflo(y3), a0); a1 = fmaf(v3, bfhi(y3), a1);
        }
        for (; j < end; ++j) {
            int2 e = edges[j];
            unsigned y = yb[(size_t)e.x * EMB2];
            float v = __int_as_float(e.y);
            a0 = fmaf(v, bflo(y), a0); a1 = fmaf(v, bfhi(y), a1);
        }
    }
    float ss = fmaf(a0, a0, a1 * a1);
#pragma unroll
    for (int off = 32; off; off >>= 1) ss += __shfl_xor(ss, off, 64);
    float sc = scale / fmaxf(sqrtf(ss), 1e-12f);
    if (lane < EMB2) {
        if (writeX) Xout[(size_t)row * EMB2 + lane] = packbf(a0, a1);
        float2* op = (float2*)(Out + (size_t)row * EMB) + lane;
        float2 o = *op;
        o.x = fmaf(a0, sc, o.x);
        o.y = fmaf(a1, sc, o.y);
        *op = o;
    }
}

extern "C" void kernel_launch(void* const* d_in, const int* in_sizes, int n_in,
                              void* d_out, int out_size, void* d_ws, size_t ws_size,
                              hipStream_t stream) {
    const float* emb   = (const float*)d_in[0];
    const float* avals = (const float*)d_in[1];
    const float* wts   = (const float*)d_in[2];
    const int*   arows = (const int*)d_in[3];
    const int*   acols = (const int*)d_in[4];

    const int N = in_sizes[0] / EMB;
    const int E = in_sizes[1];
    const int L = in_sizes[2] / (EMB * EMB);
    const float scale = 1.0f / (float)(L + 1);

    // workspace layout
    unsigned* bufY  = (unsigned*)d_ws;                    // N*EMB2 (bf16 pairs)
    unsigned* bufX  = bufY + (size_t)N * EMB2;            // N*EMB2
    int* row_ptr    = (int*)(bufX + (size_t)N * EMB2);    // N+1 (+pad)
    int* nextp      = row_ptr + (N + 2);                  // N
    int* bsum       = nextp + N;                          // 1024
    int2* edges     = (int2*)(bsum + 1024);               // E (col, val_bits)
    float* out = (float*)d_out;

    const int nb_scan = (N + 255) / 256;

    // CSR build (adjacency layer-invariant: build once, use 3x)
    hipMemsetAsync(nextp, 0, (size_t)N * sizeof(int), stream);
    k_hist<<<(E + 255) / 256, 256, 0, stream>>>(arows, nextp, E);
    k_scan1<<<nb_scan, 256, 0, stream>>>(nextp, row_ptr, bsum, N);
    k_scan2<<<1, 1024, 0, stream>>>(bsum, nb_scan);
    k_scan3<<<nb_scan, 256, 0, stream>>>(row_ptr, bsum, N, E);
    k_copy<<<nb_scan, 256, 0, stream>>>(nextp, row_ptr, N);
    k_scatter<<<(E + 255) / 256, 256, 0, stream>>>(arows, acols, avals, nextp,
                                                   edges, E);

    // out = embedding * 1/(L+1)   (layer-0 term, NOT normalized)
    k_init_out<<<2048, 256, 0, stream>>>(emb, out, (N * EMB) / 4, scale);

    const int spmm_blocks = (N + 3) / 4;   // 4 waves (rows) per 256-thr block

    // layer 0
    k_gemm_f32<<<(N + 255) / 256, 256, 0, stream>>>(emb, wts, bufY, N);
    k_spmm_norm<<<spmm_blocks, 256, 0, stream>>>(row_ptr, edges, bufY, bufX,
                                                 out, scale, 1, N);
    // layers 1..L-1
    for (int l = 1; l < L; ++l) {
        k_gemm_bf16<<<(N + 255) / 256, 256, 0, stream>>>(
            bufX, wts + (size_t)l * EMB * EMB, bufY, N);
        k_spmm_norm<<<spmm_blocks, 256, 0, stream>>>(row_ptr, edges, bufY, bufX,
                                                     out, scale, (l < L - 1) ? 1 : 0, N);
    }
}

// Round 3
// 2282.187 us; speedup vs baseline: 1.2937x; 1.0267x over previous
//
#include <hip/hip_runtime.h>

#define EMB 100
#define EMB2 50          // bf16 pairs per row
#define BSHIFT 10        // bucket = row >> 10  (<=256 buckets for N<=262144)
#define CHUNK 8192       // edges per workgroup in bucket passes

// ---- bf16 pair helpers (packed in uint: low ushort = even dim) ----
__device__ __forceinline__ float bflo(unsigned u) { return __uint_as_float(u << 16); }
__device__ __forceinline__ float bfhi(unsigned u) { return __uint_as_float(u & 0xFFFF0000u); }
__device__ __forceinline__ unsigned packbf(float a, float b) {
    unsigned ua = __float_as_uint(a), ub = __float_as_uint(b);
    unsigned ra = (ua + 0x7FFFu + ((ua >> 16) & 1u)) >> 16;   // RNE
    unsigned rb = (ub + 0x7FFFu + ((ub >> 16) & 1u)) >> 16;
    return ra | (rb << 16);
}

// ---------------- bucket count (LDS-aggregated) ----------------
__global__ __launch_bounds__(256) void k_bucket_count(const int* __restrict__ rows,
                                                      int* __restrict__ gcnt, int E) {
    __shared__ int hist[256];
    int tid = threadIdx.x;
    int base = blockIdx.x * CHUNK;
    hist[tid] = 0;
    __syncthreads();
#pragma unroll
    for (int k = 0; k < CHUNK / 256; ++k) {
        int i = base + tid + k * 256;
        if (i < E) atomicAdd(&hist[rows[i] >> BSHIFT], 1);
    }
    __syncthreads();
    if (hist[tid]) atomicAdd(&gcnt[tid], hist[tid]);
}

// ---------------- partition into row-buckets ----------------
// part[pos] = {row, col | (q14 << 18)}  with q14 = round(val * 16383)
__global__ __launch_bounds__(256) void k_partition(const int* __restrict__ rows,
                                                   const int* __restrict__ cols,
                                                   const float* __restrict__ vals,
                                                   int* __restrict__ bucket_next,
                                                   int2* __restrict__ part, int E) {
    __shared__ int hist[256];
    __shared__ int base_s[256];
    __shared__ int cnt2[256];
    int tid = threadIdx.x;
    int base = blockIdx.x * CHUNK;
    hist[tid] = 0;
    __syncthreads();
#pragma unroll
    for (int k = 0; k < CHUNK / 256; ++k) {
        int i = base + tid + k * 256;
        if (i < E) atomicAdd(&hist[rows[i] >> BSHIFT], 1);
    }
    __syncthreads();
    if (hist[tid]) base_s[tid] = atomicAdd(&bucket_next[tid], hist[tid]);
    cnt2[tid] = 0;
    __syncthreads();
#pragma unroll
    for (int k = 0; k < CHUNK / 256; ++k) {
        int i = base + tid + k * 256;
        if (i < E) {
            int r = rows[i];
            int b = r >> BSHIFT;
            unsigned q = (unsigned)__float2int_rn(vals[i] * 16383.f);
            unsigned cv = (unsigned)cols[i] | (q << 18);
            int rank = atomicAdd(&cnt2[b], 1);
            part[base_s[b] + rank] = make_int2(r, (int)cv);
        }
    }
}

// ---------------- row histogram over partitioned edges (L2-local) ------------
__global__ __launch_bounds__(256) void k_hist2(const int2* __restrict__ part,
                                               int* __restrict__ cnt, int E) {
    int i = blockIdx.x * 256 + threadIdx.x;
    if (i < E) atomicAdd(&cnt[part[i].x], 1);
}

// ---------------- final CSR scatter (L2-local) ----------------
__global__ __launch_bounds__(256) void k_scatter2(const int2* __restrict__ part,
                                                  int* __restrict__ nextp,
                                                  unsigned* __restrict__ csr, int E) {
    int i = blockIdx.x * 256 + threadIdx.x;
    if (i < E) {
        int2 e = part[i];
        int pos = atomicAdd(&nextp[e.x], 1);
        csr[pos] = (unsigned)e.y;
    }
}

// ---------------- scans ----------------
__global__ __launch_bounds__(256) void k_scan1(const int* __restrict__ cnt,
                                               int* __restrict__ outp,
                                               int* __restrict__ bsum, int n) {
    __shared__ int tmp[256];
    int i = blockIdx.x * 256 + threadIdx.x;
    int v = (i < n) ? cnt[i] : 0;
    tmp[threadIdx.x] = v;
    __syncthreads();
    for (int off = 1; off < 256; off <<= 1) {
        int t = (threadIdx.x >= off) ? tmp[threadIdx.x - off] : 0;
        __syncthreads();
        tmp[threadIdx.x] += t;
        __syncthreads();
    }
    if (i < n) outp[i] = tmp[threadIdx.x] - v;   // exclusive
    if (threadIdx.x == 255) bsum[blockIdx.x] = tmp[255];
}

__global__ __launch_bounds__(1024) void k_scan2(int* __restrict__ bsum, int nb) {
    __shared__ int tmp[1024];
    int v = (threadIdx.x < nb) ? bsum[threadIdx.x] : 0;
    tmp[threadIdx.x] = v;
    __syncthreads();
    for (int off = 1; off < 1024; off <<= 1) {
        int t = (threadIdx.x >= off) ? tmp[threadIdx.x - off] : 0;
        __syncthreads();
        tmp[threadIdx.x] += t;
        __syncthreads();
    }
    if (threadIdx.x < nb) bsum[threadIdx.x] = tmp[threadIdx.x] - v; // exclusive
}

__global__ __launch_bounds__(256) void k_scan3(int* __restrict__ outp,
                                               const int* __restrict__ bsum,
                                               int n, int E) {
    int i = blockIdx.x * 256 + threadIdx.x;
    if (i < n) outp[i] += bsum[blockIdx.x];
    if (i == 0) outp[n] = E;
}

__global__ __launch_bounds__(256) void k_copy(int* __restrict__ dst,
                                              const int* __restrict__ src, int n) {
    int i = blockIdx.x * 256 + threadIdx.x;
    if (i < n) dst[i] = src[i];
}

// ---------------- GEMM layer 0: X fp32 -> Y bf16 ----------------
__global__ __launch_bounds__(256) void k_gemm_f32(const float* __restrict__ X,
                                                  const float* __restrict__ W,
                                                  unsigned* __restrict__ Y, int N) {
    int row = blockIdx.x * 256 + threadIdx.x;
    if (row >= N) return;
    float x[EMB];
    const float4* xp = (const float4*)(X + (size_t)row * EMB);
#pragma unroll
    for (int k = 0; k < EMB / 4; ++k) {
        float4 v = xp[k];
        x[4 * k] = v.x; x[4 * k + 1] = v.y; x[4 * k + 2] = v.z; x[4 * k + 3] = v.w;
    }
    unsigned* yp = Y + (size_t)row * EMB2;
    for (int e = 0; e < EMB; e += 4) {
        const float* w0 = W + (size_t)(e + 0) * EMB;
        const float* w1 = W + (size_t)(e + 1) * EMB;
        const float* w2 = W + (size_t)(e + 2) * EMB;
        const float* w3 = W + (size_t)(e + 3) * EMB;
        float a0 = 0.f, a1 = 0.f, a2 = 0.f, a3 = 0.f;
#pragma unroll
        for (int d = 0; d < EMB; ++d) {
            float xd = x[d];
            a0 = fmaf(xd, w0[d], a0);
            a1 = fmaf(xd, w1[d], a1);
            a2 = fmaf(xd, w2[d], a2);
            a3 = fmaf(xd, w3[d], a3);
        }
        uint2 r; r.x = packbf(a0, a1); r.y = packbf(a2, a3);
        *(uint2*)(yp + e / 2) = r;
    }
}

// ---------------- GEMM layers 1+: X bf16 -> Y bf16 ----------------
__global__ __launch_bounds__(256) void k_gemm_bf16(const unsigned* __restrict__ X,
                                                   const float* __restrict__ W,
                                                   unsigned* __restrict__ Y, int N) {
    int row = blockIdx.x * 256 + threadIdx.x;
    if (row >= N) return;
    float x[EMB];
    const uint2* xp = (const uint2*)(X + (size_t)row * EMB2);
#pragma unroll
    for (int k = 0; k < EMB2 / 2; ++k) {
        uint2 u = xp[k];
        x[4 * k]     = bflo(u.x); x[4 * k + 1] = bfhi(u.x);
        x[4 * k + 2] = bflo(u.y); x[4 * k + 3] = bfhi(u.y);
    }
    unsigned* yp = Y + (size_t)row * EMB2;
    for (int e = 0; e < EMB; e += 4) {
        const float* w0 = W + (size_t)(e + 0) * EMB;
        const float* w1 = W + (size_t)(e + 1) * EMB;
        const float* w2 = W + (size_t)(e + 2) * EMB;
        const float* w3 = W + (size_t)(e + 3) * EMB;
        float a0 = 0.f, a1 = 0.f, a2 = 0.f, a3 = 0.f;
#pragma unroll
        for (int d = 0; d < EMB; ++d) {
            float xd = x[d];
            a0 = fmaf(xd, w0[d], a0);
            a1 = fmaf(xd, w1[d], a1);
            a2 = fmaf(xd, w2[d], a2);
            a3 = fmaf(xd, w3[d], a3);
        }
        uint2 r; r.x = packbf(a0, a1); r.y = packbf(a2, a3);
        *(uint2*)(yp + e / 2) = r;
    }
}

// ---------------- SpMM + norm + mean-accumulate ----------------
// One wave per row; lanes 0..49 own a bf16 pair. csr word = col | (q14<<18).
// Out[row] = prev[row]*pscale + normalized(acc)*scale
__global__ __launch_bounds__(256) void k_spmm_norm(const int* __restrict__ row_ptr,
                                                   const unsigned* __restrict__ csr,
                                                   const unsigned* __restrict__ Y,
                                                   unsigned* __restrict__ Xout,
                                                   float* __restrict__ Out,
                                                   const float* __restrict__ prev,
                                                   float pscale, float scale,
                                                   int writeX, int N) {
    int wave = (blockIdx.x * 256 + threadIdx.x) >> 6;
    int lane = threadIdx.x & 63;
    if (wave >= N) return;
    int beg = row_ptr[wave], end = row_ptr[wave + 1];
    const float dq = 1.0f / 16383.f;
    float a0 = 0.f, a1 = 0.f;
    if (lane < EMB2) {
        const unsigned* yb = Y + lane;
        int j = beg;
        for (; j + 7 < end; j += 8) {
            unsigned u0 = __builtin_nontemporal_load(&csr[j + 0]);
            unsigned u1 = __builtin_nontemporal_load(&csr[j + 1]);
            unsigned u2 = __builtin_nontemporal_load(&csr[j + 2]);
            unsigned u3 = __builtin_nontemporal_load(&csr[j + 3]);
            unsigned u4 = __builtin_nontemporal_load(&csr[j + 4]);
            unsigned u5 = __builtin_nontemporal_load(&csr[j + 5]);
            unsigned u6 = __builtin_nontemporal_load(&csr[j + 6]);
            unsigned u7 = __builtin_nontemporal_load(&csr[j + 7]);
            unsigned y0 = yb[(size_t)(u0 & 0x3FFFFu) * EMB2];
            unsigned y1 = yb[(size_t)(u1 & 0x3FFFFu) * EMB2];
            unsigned y2 = yb[(size_t)(u2 & 0x3FFFFu) * EMB2];
            unsigned y3 = yb[(size_t)(u3 & 0x3FFFFu) * EMB2];
            unsigned y4 = yb[(size_t)(u4 & 0x3FFFFu) * EMB2];
            unsigned y5 = yb[(size_t)(u5 & 0x3FFFFu) * EMB2];
            unsigned y6 = yb[(size_t)(u6 & 0x3FFFFu) * EMB2];
            unsigned y7 = yb[(size_t)(u7 & 0x3FFFFu) * EMB2];
            float v0 = (float)(u0 >> 18) * dq, v1 = (float)(u1 >> 18) * dq;
            float v2 = (float)(u2 >> 18) * dq, v3 = (float)(u3 >> 18) * dq;
            float v4 = (float)(u4 >> 18) * dq, v5 = (float)(u5 >> 18) * dq;
            float v6 = (float)(u6 >> 18) * dq, v7 = (float)(u7 >> 18) * dq;
            a0 = fmaf(v0, bflo(y0), a0); a1 = fmaf(v0, bfhi(y0), a1);
            a0 = fmaf(v1, bflo(y1), a0); a1 = fmaf(v1, bfhi(y1), a1);
            a0 = fmaf(v2, bflo(y2), a0); a1 = fmaf(v2, bfhi(y2), a1);
            a0 = fmaf(v3, bflo(y3), a0); a1 = fmaf(v3, bfhi(y3), a1);
            a0 = fmaf(v4, bflo(y4), a0); a1 = fmaf(v4, bfhi(y4), a1);
            a0 = fmaf(v5, bflo(y5), a0); a1 = fmaf(v5, bfhi(y5), a1);
            a0 = fmaf(v6, bflo(y6), a0); a1 = fmaf(v6, bfhi(y6), a1);
            a0 = fmaf(v7, bflo(y7), a0); a1 = fmaf(v7, bfhi(y7), a1);
        }
        for (; j < end; ++j) {
            unsigned u = csr[j];
            unsigned y = yb[(size_t)(u & 0x3FFFFu) * EMB2];
            float v = (float)(u >> 18) * dq;
            a0 = fmaf(v, bflo(y), a0); a1 = fmaf(v, bfhi(y), a1);
        }
    }
    float ss = fmaf(a0, a0, a1 * a1);
#pragma unroll
    for (int off = 32; off; off >>= 1) ss += __shfl_xor(ss, off, 64);
    float sc = scale / fmaxf(sqrtf(ss), 1e-12f);
    if (lane < EMB2) {
        if (writeX) Xout[(size_t)wave * EMB2 + lane] = packbf(a0, a1);
        float2 p = *((const float2*)(prev + (size_t)wave * EMB) + lane);
        float2 o;
        o.x = fmaf(a0, sc, p.x * pscale);
        o.y = fmaf(a1, sc, p.y * pscale);
        *((float2*)(Out + (size_t)wave * EMB) + lane) = o;
    }
}

extern "C" void kernel_launch(void* const* d_in, const int* in_sizes, int n_in,
                              void* d_out, int out_size, void* d_ws, size_t ws_size,
                              hipStream_t stream) {
    const float* emb   = (const float*)d_in[0];
    const float* avals = (const float*)d_in[1];
    const float* wts   = (const float*)d_in[2];
    const int*   arows = (const int*)d_in[3];
    const int*   acols = (const int*)d_in[4];

    const int N = in_sizes[0] / EMB;
    const int E = in_sizes[1];
    const int L = in_sizes[2] / (EMB * EMB);
    const float scale = 1.0f / (float)(L + 1);
    const int NB = (N + ((1 << BSHIFT) - 1)) >> BSHIFT;   // row buckets

    // workspace layout (dwords)
    unsigned* bufY        = (unsigned*)d_ws;              // N*EMB2
    unsigned* bufX        = bufY + (size_t)N * EMB2;      // N*EMB2
    int* row_ptr          = (int*)(bufX + (size_t)N * EMB2); // N+2
    int* nextp            = row_ptr + (N + 2);            // N
    int* bsum             = nextp + N;                    // 1024
    int* bucket_next      = bsum + 1024;                  // 256
    unsigned* csr         = (unsigned*)(bucket_next + 256);  // E
    size_t ofs = (size_t)2 * N * EMB2 + (N + 2) + N + 1024 + 256 + E;
    ofs = (ofs + 1) & ~(size_t)1;                         // int2 align
    int2* part            = (int2*)((unsigned*)d_ws + ofs);  // E int2
    float* out = (float*)d_out;

    const int nb_scan = (N + 255) / 256;
    const int nchunk = (E + CHUNK - 1) / CHUNK;

    // ---- CSR build: bucket partition, then L2-local hist + scatter ----
    hipMemsetAsync(bucket_next, 0, 256 * sizeof(int), stream);
    hipMemsetAsync(nextp, 0, (size_t)N * sizeof(int), stream);
    k_bucket_count<<<nchunk, 256, 0, stream>>>(arows, bucket_next, E);
    k_scan2<<<1, 1024, 0, stream>>>(bucket_next, NB);
    k_partition<<<nchunk, 256, 0, stream>>>(arows, acols, avals, bucket_next,
                                            part, E);
    k_hist2<<<(E + 255) / 256, 256, 0, stream>>>(part, nextp, E);
    k_scan1<<<nb_scan, 256, 0, stream>>>(nextp, row_ptr, bsum, N);
    k_scan2<<<1, 1024, 0, stream>>>(bsum, nb_scan);
    k_scan3<<<nb_scan, 256, 0, stream>>>(row_ptr, bsum, N, E);
    k_copy<<<nb_scan, 256, 0, stream>>>(nextp, row_ptr, N);
    k_scatter2<<<(E + 255) / 256, 256, 0, stream>>>(part, nextp, csr, E);

    const int spmm_blocks = (N + 3) / 4;   // 4 waves (rows) per 256-thr block

    // layer 0: Out = emb*scale + norm0*scale   (folds the init pass)
    k_gemm_f32<<<(N + 255) / 256, 256, 0, stream>>>(emb, wts, bufY, N);
    k_spmm_norm<<<spmm_blocks, 256, 0, stream>>>(row_ptr, csr, bufY, bufX,
                                                 out, emb, scale, scale, 1, N);
    // layers 1..L-1: Out += norm_l*scale
    for (int l = 1; l < L; ++l) {
        k_gemm_bf16<<<(N + 255) / 256, 256, 0, stream>>>(
            bufX, wts + (size_t)l * EMB * EMB, bufY, N);
        k_spmm_norm<<<spmm_blocks, 256, 0, stream>>>(row_ptr, csr, bufY, bufX,
                                                     out, out, 1.0f, scale,
                                                     (l < L - 1) ? 1 : 0, N);
    }
}

// Round 4
// 1532.342 us; speedup vs baseline: 1.9267x; 1.4893x over previous
//
#include <hip/hip_runtime.h>

#define EMB 100
#define EMB2 50          // bf16 pairs per row (valid)
#define XSTRIDE 52       // padded row stride in dwords (16B-aligned rows)
#define BSHIFT 10        // bucket = row >> 10
#define CHUNK 8192       // edges per workgroup in bucket passes

typedef __attribute__((ext_vector_type(8))) short short8;
typedef __attribute__((ext_vector_type(4))) float f32x4;

// ---- bf16 helpers (packed in uint: low ushort = even elem) ----
__device__ __forceinline__ float bflo(unsigned u) { return __uint_as_float(u << 16); }
__device__ __forceinline__ float bfhi(unsigned u) { return __uint_as_float(u & 0xFFFF0000u); }
__device__ __forceinline__ unsigned packbf(float a, float b) {
    unsigned ua = __float_as_uint(a), ub = __float_as_uint(b);
    unsigned ra = (ua + 0x7FFFu + ((ua >> 16) & 1u)) >> 16;   // RNE
    unsigned rb = (ub + 0x7FFFu + ((ub >> 16) & 1u)) >> 16;
    return ra | (rb << 16);
}
__device__ __forceinline__ unsigned short bf16rne(float f) {
    unsigned u = __float_as_uint(f);
    return (unsigned short)((u + 0x7FFFu + ((u >> 16) & 1u)) >> 16);
}

// ---------------- bucket count (LDS-aggregated) ----------------
__global__ __launch_bounds__(256) void k_bucket_count(const int* __restrict__ rows,
                                                      int* __restrict__ gcnt, int E) {
    __shared__ int hist[256];
    int tid = threadIdx.x;
    int base = blockIdx.x * CHUNK;
    hist[tid] = 0;
    __syncthreads();
#pragma unroll
    for (int k = 0; k < CHUNK / 256; ++k) {
        int i = base + tid + k * 256;
        if (i < E) atomicAdd(&hist[rows[i] >> BSHIFT], 1);
    }
    __syncthreads();
    if (hist[tid]) atomicAdd(&gcnt[tid], hist[tid]);
}

// ---------------- partition into row-buckets ----------------
__global__ __launch_bounds__(256) void k_partition(const int* __restrict__ rows,
                                                   const int* __restrict__ cols,
                                                   const float* __restrict__ vals,
                                                   int* __restrict__ bucket_next,
                                                   int2* __restrict__ part, int E) {
    __shared__ int hist[256];
    __shared__ int base_s[256];
    __shared__ int cnt2[256];
    int tid = threadIdx.x;
    int base = blockIdx.x * CHUNK;
    hist[tid] = 0;
    __syncthreads();
#pragma unroll
    for (int k = 0; k < CHUNK / 256; ++k) {
        int i = base + tid + k * 256;
        if (i < E) atomicAdd(&hist[rows[i] >> BSHIFT], 1);
    }
    __syncthreads();
    if (hist[tid]) base_s[tid] = atomicAdd(&bucket_next[tid], hist[tid]);
    cnt2[tid] = 0;
    __syncthreads();
#pragma unroll
    for (int k = 0; k < CHUNK / 256; ++k) {
        int i = base + tid + k * 256;
        if (i < E) {
            int r = rows[i];
            int b = r >> BSHIFT;
            unsigned q = (unsigned)__float2int_rn(vals[i] * 16383.f);
            unsigned cv = (unsigned)cols[i] | (q << 18);
            int rank = atomicAdd(&cnt2[b], 1);
            part[base_s[b] + rank] = make_int2(r, (int)cv);
        }
    }
}

// ---------------- row histogram over partitioned edges (L2-local) ------------
__global__ __launch_bounds__(256) void k_hist2(const int2* __restrict__ part,
                                               int* __restrict__ cnt, int E) {
    int i = blockIdx.x * 256 + threadIdx.x;
    if (i < E) atomicAdd(&cnt[part[i].x], 1);
}

// ---------------- final CSR scatter (L2-local) ----------------
__global__ __launch_bounds__(256) void k_scatter2(const int2* __restrict__ part,
                                                  int* __restrict__ nextp,
                                                  unsigned* __restrict__ csr, int E) {
    int i = blockIdx.x * 256 + threadIdx.x;
    if (i < E) {
        int2 e = part[i];
        int pos = atomicAdd(&nextp[e.x], 1);
        csr[pos] = (unsigned)e.y;
    }
}

// ---------------- scans ----------------
__global__ __launch_bounds__(256) void k_scan1(const int* __restrict__ cnt,
                                               int* __restrict__ outp,
                                               int* __restrict__ bsum, int n) {
    __shared__ int tmp[256];
    int i = blockIdx.x * 256 + threadIdx.x;
    int v = (i < n) ? cnt[i] : 0;
    tmp[threadIdx.x] = v;
    __syncthreads();
    for (int off = 1; off < 256; off <<= 1) {
        int t = (threadIdx.x >= off) ? tmp[threadIdx.x - off] : 0;
        __syncthreads();
        tmp[threadIdx.x] += t;
        __syncthreads();
    }
    if (i < n) outp[i] = tmp[threadIdx.x] - v;   // exclusive
    if (threadIdx.x == 255) bsum[blockIdx.x] = tmp[255];
}

__global__ __launch_bounds__(1024) void k_scan2(int* __restrict__ bsum, int nb) {
    __shared__ int tmp[1024];
    int v = (threadIdx.x < nb) ? bsum[threadIdx.x] : 0;
    tmp[threadIdx.x] = v;
    __syncthreads();
    for (int off = 1; off < 1024; off <<= 1) {
        int t = (threadIdx.x >= off) ? tmp[threadIdx.x - off] : 0;
        __syncthreads();
        tmp[threadIdx.x] += t;
        __syncthreads();
    }
    if (threadIdx.x < nb) bsum[threadIdx.x] = tmp[threadIdx.x] - v; // exclusive
}

__global__ __launch_bounds__(256) void k_scan3(int* __restrict__ outp,
                                               const int* __restrict__ bsum,
                                               int n, int E) {
    int i = blockIdx.x * 256 + threadIdx.x;
    if (i < n) outp[i] += bsum[blockIdx.x];
    if (i == 0) outp[n] = E;
}

__global__ __launch_bounds__(256) void k_copy(int* __restrict__ dst,
                                              const int* __restrict__ src, int n) {
    int i = blockIdx.x * 256 + threadIdx.x;
    if (i < n) dst[i] = src[i];
}

// ---------------- MFMA GEMM: Y[r][e] = sum_d X[r][d] * W[e][d] ----------------
// A[m][k] = X[rowbase+m][k]  (m = lane&15, k = (lane>>4)*8 + j)
// B[k][n] = W[nt*16+n][k]    (n = lane&15, same k), staged bf16 in LDS
// C/D: col = lane&15, row = (lane>>4)*4 + reg   [verified layout]
template <bool F32SRC>
__global__ __launch_bounds__(256) void k_gemm_mfma(const void* __restrict__ Xv,
                                                   const float* __restrict__ W,
                                                   unsigned* __restrict__ Y,
                                                   int nTiles, int N) {
    __shared__ uint4 Bf[28][64];   // [nt*4+ks][lane]
    int tid = threadIdx.x;
    // ---- build B fragments (bf16, zero-padded e>=100 / d>=100) ----
#pragma unroll
    for (int it = 0; it < 7; ++it) {
        int id = it * 256 + tid;
        int fs = id >> 6, lane = id & 63;
        int nt = fs >> 2, ks = fs & 3;
        int e = nt * 16 + (lane & 15);
        int dbase = ks * 32 + (lane >> 4) * 8;
        float w[8];
#pragma unroll
        for (int j = 0; j < 8; ++j) {
            int d = dbase + j;
            w[j] = (e < EMB && d < EMB) ? W[e * EMB + d] : 0.f;
        }
        uint4 u;
        u.x = packbf(w[0], w[1]); u.y = packbf(w[2], w[3]);
        u.z = packbf(w[4], w[5]); u.w = packbf(w[6], w[7]);
        Bf[fs][lane] = u;
    }
    __syncthreads();

    int wid = (blockIdx.x * 256 + tid) >> 6;
    int nWaves = gridDim.x * 4;
    int lane = tid & 63;
    int m = lane & 15, kg = lane >> 4;

    for (int tile = wid; tile < nTiles; tile += nWaves) {
        int rowbase = tile * 16;
        int arow = rowbase + m; if (arow >= N) arow = N - 1;   // clamp (masked at store)
        uint4 a[4];
        if (F32SRC) {
            const float* xr = (const float*)Xv + (size_t)arow * EMB;
#pragma unroll
            for (int ks = 0; ks < 3; ++ks) {
                float4 v0 = *(const float4*)(xr + ks * 32 + kg * 8);
                float4 v1 = *(const float4*)(xr + ks * 32 + kg * 8 + 4);
                a[ks] = make_uint4(packbf(v0.x, v0.y), packbf(v0.z, v0.w),
                                   packbf(v1.x, v1.y), packbf(v1.z, v1.w));
            }
            uint4 t = make_uint4(0, 0, 0, 0);
            if (kg == 0) { float4 v = *(const float4*)(xr + 96);
                           t.x = packbf(v.x, v.y); t.y = packbf(v.z, v.w); }
            a[3] = t;
        } else {
            const unsigned* xr = (const unsigned*)Xv + (size_t)arow * XSTRIDE;
#pragma unroll
            for (int ks = 0; ks < 3; ++ks)
                a[ks] = *(const uint4*)(xr + ks * 16 + kg * 4);
            uint4 t = make_uint4(0, 0, 0, 0);
            if (kg == 0) { uint2 v = *(const uint2*)(xr + 48); t.x = v.x; t.y = v.y; }
            a[3] = t;
        }

        f32x4 acc[7];
#pragma unroll
        for (int nt = 0; nt < 7; ++nt) acc[nt] = (f32x4){0.f, 0.f, 0.f, 0.f};
#pragma unroll
        for (int ks = 0; ks < 4; ++ks) {
            short8 av = __builtin_bit_cast(short8, a[ks]);
#pragma unroll
            for (int nt = 0; nt < 7; ++nt) {
                short8 bv = __builtin_bit_cast(short8, Bf[nt * 4 + ks][lane]);
                acc[nt] = __builtin_amdgcn_mfma_f32_16x16x32_bf16(av, bv, acc[nt], 0, 0, 0);
            }
        }
        // epilogue: bf16 store, row stride = XSTRIDE*2 ushorts
        unsigned short* Yu = (unsigned short*)Y;
#pragma unroll
        for (int nt = 0; nt < 7; ++nt) {
            int e = nt * 16 + m;
            if (e < EMB) {
#pragma unroll
                for (int r = 0; r < 4; ++r) {
                    int rr = rowbase + kg * 4 + r;
                    if (rr < N)
                        Yu[(size_t)rr * (XSTRIDE * 2) + e] = bf16rne(acc[nt][r]);
                }
            }
        }
    }
}

// ---------------- SpMM + norm + mean-accumulate ----------------
// One wave per row; lanes 0..49 own a bf16 pair. csr word = col | (q14<<18).
// Out[row] = prev[row]*pscale + normalized(acc)*scale
__global__ __launch_bounds__(256) void k_spmm_norm(const int* __restrict__ row_ptr,
                                                   const unsigned* __restrict__ csr,
                                                   const unsigned* __restrict__ Y,
                                                   unsigned* __restrict__ Xout,
                                                   float* __restrict__ Out,
                                                   const float* __restrict__ prev,
                                                   float pscale, float scale,
                                                   int writeX, int N) {
    int wave = (blockIdx.x * 256 + threadIdx.x) >> 6;
    int lane = threadIdx.x & 63;
    if (wave >= N) return;
    int beg = row_ptr[wave], end = row_ptr[wave + 1];
    const float dq = 1.0f / 16383.f;
    float a0 = 0.f, a1 = 0.f;
    if (lane < EMB2) {
        const unsigned* yb = Y + lane;
        int j = beg;
        for (; j + 7 < end; j += 8) {
            unsigned u0 = __builtin_nontemporal_load(&csr[j + 0]);
            unsigned u1 = __builtin_nontemporal_load(&csr[j + 1]);
            unsigned u2 = __builtin_nontemporal_load(&csr[j + 2]);
            unsigned u3 = __builtin_nontemporal_load(&csr[j + 3]);
            unsigned u4 = __builtin_nontemporal_load(&csr[j + 4]);
            unsigned u5 = __builtin_nontemporal_load(&csr[j + 5]);
            unsigned u6 = __builtin_nontemporal_load(&csr[j + 6]);
            unsigned u7 = __builtin_nontemporal_load(&csr[j + 7]);
            unsigned y0 = yb[(size_t)(u0 & 0x3FFFFu) * XSTRIDE];
            unsigned y1 = yb[(size_t)(u1 & 0x3FFFFu) * XSTRIDE];
            unsigned y2 = yb[(size_t)(u2 & 0x3FFFFu) * XSTRIDE];
            unsigned y3 = yb[(size_t)(u3 & 0x3FFFFu) * XSTRIDE];
            unsigned y4 = yb[(size_t)(u4 & 0x3FFFFu) * XSTRIDE];
            unsigned y5 = yb[(size_t)(u5 & 0x3FFFFu) * XSTRIDE];
            unsigned y6 = yb[(size_t)(u6 & 0x3FFFFu) * XSTRIDE];
            unsigned y7 = yb[(size_t)(u7 & 0x3FFFFu) * XSTRIDE];
            float v0 = (float)(u0 >> 18) * dq, v1 = (float)(u1 >> 18) * dq;
            float v2 = (float)(u2 >> 18) * dq, v3 = (float)(u3 >> 18) * dq;
            float v4 = (float)(u4 >> 18) * dq, v5 = (float)(u5 >> 18) * dq;
            float v6 = (float)(u6 >> 18) * dq, v7 = (float)(u7 >> 18) * dq;
            a0 = fmaf(v0, bflo(y0), a0); a1 = fmaf(v0, bfhi(y0), a1);
            a0 = fmaf(v1, bflo(y1), a0); a1 = fmaf(v1, bfhi(y1), a1);
            a0 = fmaf(v2, bflo(y2), a0); a1 = fmaf(v2, bfhi(y2), a1);
            a0 = fmaf(v3, bflo(y3), a0); a1 = fmaf(v3, bfhi(y3), a1);
            a0 = fmaf(v4, bflo(y4), a0); a1 = fmaf(v4, bfhi(y4), a1);
            a0 = fmaf(v5, bflo(y5), a0); a1 = fmaf(v5, bfhi(y5), a1);
            a0 = fmaf(v6, bflo(y6), a0); a1 = fmaf(v6, bfhi(y6), a1);
            a0 = fmaf(v7, bflo(y7), a0); a1 = fmaf(v7, bfhi(y7), a1);
        }
        for (; j < end; ++j) {
            unsigned u = csr[j];
            unsigned y = yb[(size_t)(u & 0x3FFFFu) * XSTRIDE];
            float v = (float)(u >> 18) * dq;
            a0 = fmaf(v, bflo(y), a0); a1 = fmaf(v, bfhi(y), a1);
        }
    }
    float ss = fmaf(a0, a0, a1 * a1);
#pragma unroll
    for (int off = 32; off; off >>= 1) ss += __shfl_xor(ss, off, 64);
    float sc = scale / fmaxf(sqrtf(ss), 1e-12f);
    if (lane < EMB2) {
        if (writeX) Xout[(size_t)wave * XSTRIDE + lane] = packbf(a0, a1);
        float2 p = *((const float2*)(prev + (size_t)wave * EMB) + lane);
        float2 o;
        o.x = fmaf(a0, sc, p.x * pscale);
        o.y = fmaf(a1, sc, p.y * pscale);
        *((float2*)(Out + (size_t)wave * EMB) + lane) = o;
    }
}

extern "C" void kernel_launch(void* const* d_in, const int* in_sizes, int n_in,
                              void* d_out, int out_size, void* d_ws, size_t ws_size,
                              hipStream_t stream) {
    const float* emb   = (const float*)d_in[0];
    const float* avals = (const float*)d_in[1];
    const float* wts   = (const float*)d_in[2];
    const int*   arows = (const int*)d_in[3];
    const int*   acols = (const int*)d_in[4];

    const int N = in_sizes[0] / EMB;
    const int E = in_sizes[1];
    const int L = in_sizes[2] / (EMB * EMB);
    const float scale = 1.0f / (float)(L + 1);
    const int NB = (N + ((1 << BSHIFT) - 1)) >> BSHIFT;

    // workspace layout (dwords). `part` aliases bufY/bufX (only live pre-GEMM).
    unsigned* bufY   = (unsigned*)d_ws;                      // N*XSTRIDE
    unsigned* bufX   = bufY + (size_t)N * XSTRIDE;           // N*XSTRIDE
    int* row_ptr     = (int*)(bufX + (size_t)N * XSTRIDE);   // N+2
    int* nextp       = row_ptr + (N + 2);                    // N
    int* bsum        = nextp + N;                            // 1024
    int* bucket_next = bsum + 1024;                          // 256
    unsigned* csr    = (unsigned*)(bucket_next + 256);       // E
    int2* part       = (int2*)d_ws;                          // E int2 (aliased)
    float* out = (float*)d_out;

    const int nb_scan = (N + 255) / 256;
    const int nchunk = (E + CHUNK - 1) / CHUNK;

    // ---- CSR build: bucket partition, then L2-local hist + scatter ----
    hipMemsetAsync(bucket_next, 0, 256 * sizeof(int), stream);
    hipMemsetAsync(nextp, 0, (size_t)N * sizeof(int), stream);
    k_bucket_count<<<nchunk, 256, 0, stream>>>(arows, bucket_next, E);
    k_scan2<<<1, 1024, 0, stream>>>(bucket_next, NB);
    k_partition<<<nchunk, 256, 0, stream>>>(arows, acols, avals, bucket_next,
                                            part, E);
    k_hist2<<<(E + 255) / 256, 256, 0, stream>>>(part, nextp, E);
    k_scan1<<<nb_scan, 256, 0, stream>>>(nextp, row_ptr, bsum, N);
    k_scan2<<<1, 1024, 0, stream>>>(bsum, nb_scan);
    k_scan3<<<nb_scan, 256, 0, stream>>>(row_ptr, bsum, N, E);
    k_copy<<<nb_scan, 256, 0, stream>>>(nextp, row_ptr, N);
    k_scatter2<<<(E + 255) / 256, 256, 0, stream>>>(part, nextp, csr, E);

    const int nTiles = (N + 15) / 16;
    const int gemm_blocks = 782;
    const int spmm_blocks = (N + 3) / 4;

    // layer 0: Out = emb*scale + norm0*scale
    k_gemm_mfma<true><<<gemm_blocks, 256, 0, stream>>>(emb, wts, bufY, nTiles, N);
    k_spmm_norm<<<spmm_blocks, 256, 0, stream>>>(row_ptr, csr, bufY, bufX,
                                                 out, emb, scale, scale, 1, N);
    // layers 1..L-1: Out += norm_l*scale
    for (int l = 1; l < L; ++l) {
        k_gemm_mfma<false><<<gemm_blocks, 256, 0, stream>>>(
            bufX, wts + (size_t)l * EMB * EMB, bufY, nTiles, N);
        k_spmm_norm<<<spmm_blocks, 256, 0, stream>>>(row_ptr, csr, bufY, bufX,
                                                     out, out, 1.0f, scale,
                                                     (l < L - 1) ? 1 : 0, N);
    }
}